// Round 5
// baseline (620.471 us; speedup 1.0000x reference)
//
#include <hip/hip_runtime.h>
#include <stdint.h>

#define DIM 512
#define ROWS_PER_BLOCK 64
#define N_CHUNKS 32                      // 32 chunks of 16 e-columns
#define CHUNK_BYTES 8192                 // 16 rows x 512 fp8 (atom-rotated)
#define WS_BYTES (N_CHUNKS * CHUNK_BYTES)   // 262144

typedef __attribute__((ext_vector_type(4))) float f32x4;
typedef __attribute__((ext_vector_type(2))) float f32x2;
typedef __attribute__((ext_vector_type(4))) int   i32x4;

// k-permutation (validated rounds 1-4): position q = g*8+j within 32-k block kk
// holds k = 32*kk + (j<4 ? 4g+j : 16+4g+(j-4)). Puts epilogue value delta[r][e]
// in-lane: e = 16*eb + 4g + i <-> fragL[eb>>1], byte (eb&1)*4 + i.
static __device__ __forceinline__ int kperm(int kk, int q) {
  int g = q >> 3, j = q & 7;
  int r = (j < 4) ? (g * 4 + j) : (16 + g * 4 + (j - 4));
  return kk * 32 + r;
}

// fp8 image of 64*(S - I), pre-swizzled (validated round 4): chunk -> 16 rows
// (e_l) x 512 B; within a row, logical atom 4P+g stored at slot ((4P+g)+e_l)&31.
__global__ void prep_R(const float* __restrict__ S, uint32_t* __restrict__ ws) {
  int idx = blockIdx.x * blockDim.x + threadIdx.x;   // word index
  if (idx >= WS_BYTES / 4) return;
  int b     = idx * 4;
  int chunk = b >> 13;
  int e_l   = (b >> 9) & 15;
  int inrow = b & 511;
  int slot  = inrow >> 4;
  int bia   = inrow & 15;
  int la    = (slot - e_l) & 31;         // logical atom = 4P+g
  int P = la >> 2, g = la & 3;
  int e = chunk * 16 + e_l;
  float v[4];
#pragma unroll
  for (int t = 0; t < 4; ++t) {
    int bb = bia + t;
    int j  = bb & 7;
    int kk = 2 * P + (bb >> 3);
    int k  = kperm(kk, g * 8 + j);
    v[t] = 64.0f * (S[k * DIM + e] - (k == e ? 1.0f : 0.0f));   // x64: e4m3 range
  }
  int w = __builtin_amdgcn_cvt_pk_fp8_f32(v[0], v[1], 0, false);
  w     = __builtin_amdgcn_cvt_pk_fp8_f32(v[2], v[3], w, true);
  ws[idx] = (uint32_t)w;
}

// Stage one 8 KB R-chunk into LDS (async direct-to-LDS, width 16, lane-linear).
static __device__ __forceinline__ void stage_chunk(const uint32_t* __restrict__ ws,
                                                   int eb, char* dst, int tid) {
  const uint32_t* src = ws + (size_t)eb * (CHUNK_BYTES / 4);
#pragma unroll
  for (int r = 0; r < 2; ++r) {
    int idx = r * 256 + tid;
    __builtin_amdgcn_global_load_lds(
        (const __attribute__((address_space(1))) void*)(src + idx * 4),
        (__attribute__((address_space(3))) void*)(dst + idx * 16),
        16, 0, 0);
  }
}

// Stage a 64-row x 256 B k-slice (sub-step s) of a 64x512-f32 row-block into
// LDS, lane-linear on the LDS side (DMA requirement). The bank de-conflict
// XOR-swizzle is applied to the GLOBAL source address: linear LDS atom
// (row,c) holds global atom (row, c ^ (row&15)). Consumers read atom t of row
// m at LDS (row*256 + ((t^m)<<4)) -> 2-way max bank aliasing (free).
static __device__ __forceinline__ void stage_sub(const char* __restrict__ srcbase,
                                                 int s, char* dst, int tid) {
#pragma unroll
  for (int r = 0; r < 4; ++r) {                      // 1024 x 16B atoms
    int A   = r * 256 + tid;
    int row = A >> 4, c = A & 15;
    const char* src = srcbase + row * 2048 + s * 256 + ((c ^ (row & 15)) << 4);
    __builtin_amdgcn_global_load_lds(
        (const __attribute__((address_space(1))) void*)src,
        (__attribute__((address_space(3))) void*)(dst + A * 16),
        16, 0, 0);
  }
}

static __device__ __forceinline__ long long pack_delta(const f32x4& xa, const f32x4& xc,
                                                       const f32x4& fa, const f32x4& fc,
                                                       float& sumsq) {
  float d0 = xa[0] - fa[0], d1 = xa[1] - fa[1], d2 = xa[2] - fa[2], d3 = xa[3] - fa[3];
  float d4 = xc[0] - fc[0], d5 = xc[1] - fc[1], d6 = xc[2] - fc[2], d7 = xc[3] - fc[3];
  sumsq += d0*d0 + d1*d1 + d2*d2 + d3*d3 + d4*d4 + d5*d5 + d6*d6 + d7*d7;
  int lo = __builtin_amdgcn_cvt_pk_fp8_f32(d0, d1, 0, false);
  lo     = __builtin_amdgcn_cvt_pk_fp8_f32(d2, d3, lo, true);
  int hi = __builtin_amdgcn_cvt_pk_fp8_f32(d4, d5, 0, false);
  hi     = __builtin_amdgcn_cvt_pk_fp8_f32(d6, d7, hi, true);
  return (long long)(((unsigned long long)(unsigned)hi << 32) | (unsigned)lo);
}

// Consume sub-step S from LDS: build fragL[2S], fragL[2S+1] (constant indices).
template <int S>
struct P0 {
  static __device__ __forceinline__ void run(const char* __restrict__ xrow,
                                             const char* __restrict__ frow,
                                             int g, int m,
                                             long long (&fragL)[16], float& sumsq) {
    {
      const int t0 = g, t1 = 4 + g;                  // KK block 2S
      f32x4 xa = *(const f32x4*)(xrow + ((t0 ^ m) << 4));
      f32x4 xc = *(const f32x4*)(xrow + ((t1 ^ m) << 4));
      f32x4 fa = *(const f32x4*)(frow + ((t0 ^ m) << 4));
      f32x4 fc = *(const f32x4*)(frow + ((t1 ^ m) << 4));
      fragL[2 * S] = pack_delta(xa, xc, fa, fc, sumsq);
    }
    {
      const int t0 = 8 + g, t1 = 12 + g;             // KK block 2S+1
      f32x4 xa = *(const f32x4*)(xrow + ((t0 ^ m) << 4));
      f32x4 xc = *(const f32x4*)(xrow + ((t1 ^ m) << 4));
      f32x4 fa = *(const f32x4*)(frow + ((t0 ^ m) << 4));
      f32x4 fc = *(const f32x4*)(frow + ((t1 ^ m) << 4));
      fragL[2 * S + 1] = pack_delta(xa, xc, fa, fc, sumsq);
    }
  }
};

// Phase-0 sub-step loop: barrier (DMA S visible) -> consume -> barrier (WAR) ->
// DMA S+1. HBM latency is hidden by the 64 KB/block in flight per sub-step.
template <int S>
struct SubLoop {
  static __device__ __forceinline__ void run(const char* Xb, const char* Fb,
                                             char* sX, char* sF,
                                             const char* xrow, const char* frow,
                                             int tid, int g, int m,
                                             long long (&fragL)[16], float& sumsq) {
    __syncthreads();                                 // drains vmcnt: slice S ready
    P0<S>::run(xrow, frow, g, m, fragL, sumsq);
    __syncthreads();                                 // WAR: all waves done reading
    if (S < 7) {
      stage_sub(Xb, S + 1, sX, tid);
      stage_sub(Fb, S + 1, sF, tid);
    }
    SubLoop<S + 1>::run(Xb, Fb, sX, sF, xrow, frow, tid, g, m, fragL, sumsq);
  }
};
template <>
struct SubLoop<8> {
  static __device__ __forceinline__ void run(const char*, const char*, char*, char*,
                                             const char*, const char*, int, int, int,
                                             long long (&)[16], float&) {}
};

// ---- K-loop over 8 atom-steps; each b128 feeds two fp8 MFMAs (round 4) ----
template <int P>
struct KLoop {
  static __device__ __forceinline__ void run(const char* __restrict__ rowbase,
                                             int g, int m,
                                             const long long (&fragL)[16],
                                             f32x4& c0, f32x4& c1) {
    int off = ((4 * P + g + m) & 31) * 16;           // rotated atom slot
    i32x4 a = *(const i32x4*)(rowbase + off);
    long long A0 = (long long)(((unsigned long long)(unsigned)a[1] << 32) | (unsigned)a[0]);
    long long A1 = (long long)(((unsigned long long)(unsigned)a[3] << 32) | (unsigned)a[2]);
    c0 = __builtin_amdgcn_mfma_f32_16x16x32_fp8_fp8(A0, fragL[2 * P],     c0, 0, 0, 0);
    c1 = __builtin_amdgcn_mfma_f32_16x16x32_fp8_fp8(A1, fragL[2 * P + 1], c1, 0, 0, 0);
    KLoop<P + 1>::run(rowbase, g, m, fragL, c0, c1);
  }
};
template <>
struct KLoop<8> {
  static __device__ __forceinline__ void run(const char*, int, int,
                                             const long long (&)[16], f32x4&, f32x4&) {}
};

// ---- Chunk loop, double-buffered (round 4, validated) ----
template <int EB>
struct ChunkLoop {
  static __device__ __forceinline__ void run(const uint32_t* __restrict__ ws,
                                             char* sA0, char* sA1,
                                             int tid, int m, int g,
                                             const long long (&fragL)[16], float& part) {
    char* cur = (EB & 1) ? sA1 : sA0;
    char* nxt = (EB & 1) ? sA0 : sA1;
    if (EB + 1 < N_CHUNKS) stage_chunk(ws, EB + 1, nxt, tid);

    f32x4 c0 = {0.f, 0.f, 0.f, 0.f}, c1 = {0.f, 0.f, 0.f, 0.f};
    KLoop<0>::run(cur + m * 512, g, m, fragL, c0, c1);

    constexpr int kk = EB >> 1;
    int src = (int)(fragL[kk] >> ((EB & 1) * 32));
    f32x2 f01 = __builtin_amdgcn_cvt_pk_f32_fp8(src, false);
    f32x2 f23 = __builtin_amdgcn_cvt_pk_f32_fp8(src, true);
    part += (c0[0] + c1[0]) * f01[0] + (c0[1] + c1[1]) * f01[1]
          + (c0[2] + c1[2]) * f23[0] + (c0[3] + c1[3]) * f23[1];

    __syncthreads();
    ChunkLoop<EB + 1>::run(ws, sA0, sA1, tid, m, g, fragL, part);
  }
};
template <>
struct ChunkLoop<N_CHUNKS> {
  static __device__ __forceinline__ void run(const uint32_t*, char*, char*, int, int, int,
                                             const long long (&)[16], float&) {}
};

// out[row] = fp32 sumsq(delta) + (1/64) * delta^T (64R) delta  via fp8 MFMA.
// Phase 0 streams x/x_fit through LDS with global_load_lds: no VGPR load
// destinations -> 64 KB/block in flight per sub-step -> HBM-saturating MLP
// independent of occupancy (round 4 was latency-bound at ~1 TB/s).
__global__ __launch_bounds__(256, 2)
void mahal_main(const float* __restrict__ X, const float* __restrict__ XF,
                const uint32_t* __restrict__ ws, float* __restrict__ out) {
  __shared__ __align__(16) char sA[2][CHUNK_BYTES];  // R dbuf, 16 KB
  __shared__ __align__(16) char sX[16384];           // x  k-slice, 64 rows x 256 B
  __shared__ __align__(16) char sF[16384];           // xf k-slice

  const int tid  = threadIdx.x;
  const int lane = tid & 63;
  const int wv   = tid >> 6;
  const int m    = lane & 15;          // delta row within wave
  const int g    = lane >> 4;          // lane group
  const int rowl = wv * 16 + m;        // row within block

  const char* Xb = (const char*)(X  + (size_t)blockIdx.x * ROWS_PER_BLOCK * DIM);
  const char* Fb = (const char*)(XF + (size_t)blockIdx.x * ROWS_PER_BLOCK * DIM);

  // Kick off sub-step 0 (x/xf) and R chunk 0, all async.
  stage_sub(Xb, 0, sX, tid);
  stage_sub(Fb, 0, sF, tid);
  stage_chunk(ws, 0, sA[0], tid);

  const char* xrow = sX + rowl * 256;
  const char* frow = sF + rowl * 256;

  long long fragL[16];
  float sumsq = 0.f;
  SubLoop<0>::run(Xb, Fb, sX, sF, xrow, frow, tid, g, m, fragL, sumsq);
  sumsq += __shfl_xor(sumsq, 16);
  sumsq += __shfl_xor(sumsq, 32);

  // Last SubLoop barrier already synced; chunk 0 drained at first barrier.
  float part = 0.f;
  ChunkLoop<0>::run(ws, sA[0], sA[1], tid, m, g, fragL, part);

  part += __shfl_xor(part, 16);
  part += __shfl_xor(part, 32);
  if (g == 0) out[blockIdx.x * ROWS_PER_BLOCK + rowl] = sumsq + part * 0.015625f;
}

// Safety-net (only if ws_size is unexpectedly small): naive fp32, correct.
__global__ void mahal_naive(const float* __restrict__ X, const float* __restrict__ XF,
                            const float* __restrict__ S, float* __restrict__ out, int n) {
  int row = blockIdx.x * blockDim.x + threadIdx.x;
  if (row >= n) return;
  const float* xr = X + (size_t)row * DIM;
  const float* fr = XF + (size_t)row * DIM;
  float acc = 0.f;
  for (int d = 0; d < DIM; ++d) {
    float dd = xr[d] - fr[d];
    float inner = 0.f;
    for (int e = 0; e < DIM; ++e) inner += S[d * DIM + e] * (xr[e] - fr[e]);
    acc += dd * inner;
  }
  out[row] = acc;
}

extern "C" void kernel_launch(void* const* d_in, const int* in_sizes, int n_in,
                              void* d_out, int out_size, void* d_ws, size_t ws_size,
                              hipStream_t stream) {
  const float* X  = (const float*)d_in[0];
  const float* XF = (const float*)d_in[1];
  const float* S  = (const float*)d_in[2];
  float* out = (float*)d_out;
  const int N = in_sizes[0] / DIM;

  if (ws_size < (size_t)WS_BYTES || (N % ROWS_PER_BLOCK) != 0) {
    mahal_naive<<<(N + 63) / 64, 64, 0, stream>>>(X, XF, S, out, N);
    return;
  }

  uint32_t* ws = (uint32_t*)d_ws;
  prep_R<<<(WS_BYTES / 4 + 255) / 256, 256, 0, stream>>>(S, ws);
  mahal_main<<<N / ROWS_PER_BLOCK, 256, 0, stream>>>(X, XF, ws, out);
}